// Round 7
// baseline (267.346 us; speedup 1.0000x reference)
//
#include <hip/hip_runtime.h>

#define EPS_ 1e-4f

typedef _Float16 f16;
typedef _Float16 f16x8 __attribute__((ext_vector_type(8)));
typedef _Float16 f16x4 __attribute__((ext_vector_type(4)));
typedef _Float16 f16x2 __attribute__((ext_vector_type(2)));
typedef __fp16 h16x2 __attribute__((ext_vector_type(2)));
typedef float f32x4v __attribute__((ext_vector_type(4)));
typedef float f32x2v __attribute__((ext_vector_type(2)));
typedef unsigned int u32;

__device__ inline f32x4v mfma16(f16x8 a, f16x8 b, f32x4v c) {
    return __builtin_amdgcn_mfma_f32_16x16x32_f16(a, b, c, 0, 0, 0);
}
__device__ inline f16x2 pk2(float a, float b) {
    h16x2 r = __builtin_amdgcn_cvt_pkrtz(a, b);
    return __builtin_bit_cast(f16x2, r);
}
__device__ inline u32 bc32(f16x2 v) { return __builtin_bit_cast(u32, v); }

__device__ inline f16x8 zero8() {
    f16x8 r;
#pragma unroll
    for (int i = 0; i < 8; i++) r[i] = (f16)0.f;
    return r;
}

__device__ inline f16x8 cvt8x2(f32x2v a, f32x2v b, f32x2v c, f32x2v d) {
    f16x2 p0 = pk2(a.x, a.y), p1 = pk2(b.x, b.y), p2 = pk2(c.x, c.y), p3 = pk2(d.x, d.y);
    f16x8 r;
    r[0] = p0[0]; r[1] = p0[1]; r[2] = p1[0]; r[3] = p1[1];
    r[4] = p2[0]; r[5] = p2[1]; r[6] = p3[0]; r[7] = p3[1];
    return r;
}

// ---------------------------------------------------------------------------
// Kernel 1: 8x8 average pool.  sdf (2,1024,1024) -> pooled (2,128,128)
// ---------------------------------------------------------------------------
__global__ void pool_kernel(const float* __restrict__ sdf, float* __restrict__ pooled) {
    int t = blockIdx.x * blockDim.x + threadIdx.x;
    int c = t >> 14;
    int rem = t & 16383;
    int R = rem >> 7;
    int C = rem & 127;
    const float* base = sdf + c * 1048576 + (R * 8) * 1024 + C * 8;
    float sum = 0.f;
#pragma unroll
    for (int r = 0; r < 8; r++) {
        const float4* p = (const float4*)(base + r * 1024);
        float4 a = p[0];
        float4 b = p[1];
        sum += a.x + a.y + a.z + a.w + b.x + b.y + b.z + b.w;
    }
    pooled[t] = sum * (1.f / 64.f);
}

// ---------------------------------------------------------------------------
// Kernel 2: 5x5 conv, 2->16 ch, pad 2. pooled (2,128,128) -> A [(y*128+x)*16+f]
// ---------------------------------------------------------------------------
__global__ void conv_kernel(const float* __restrict__ pooled,
                            const float* __restrict__ conv_w,
                            const float* __restrict__ conv_b,
                            float* __restrict__ A) {
    int t = blockIdx.x * blockDim.x + threadIdx.x;
    int y = t >> 7, x = t & 127;
    float acc[16];
#pragma unroll
    for (int f = 0; f < 16; f++) acc[f] = conv_b[f];
#pragma unroll
    for (int c = 0; c < 2; c++) {
#pragma unroll
        for (int ky = 0; ky < 5; ky++) {
            int yy = y + ky - 2;
            if (yy < 0 || yy > 127) continue;
#pragma unroll
            for (int kx = 0; kx < 5; kx++) {
                int xx = x + kx - 2;
                if (xx < 0 || xx > 127) continue;
                float v = pooled[c * 16384 + yy * 128 + xx];
                int wbase = c * 25 + ky * 5 + kx;
#pragma unroll
                for (int f = 0; f < 16; f++)
                    acc[f] = fmaf(v, conv_w[f * 50 + wbase], acc[f]);
            }
        }
    }
    float4* out4 = (float4*)(A + t * 16);
#pragma unroll
    for (int q = 0; q < 4; q++)
        out4[q] = make_float4(acc[4 * q], acc[4 * q + 1], acc[4 * q + 2], acc[4 * q + 3]);
}

// ---------------------------------------------------------------------------
// Feature (k) order for layer 1:
//   k 0..49 = sse[0..49]; k50,51 = x0,x1; k52 = s; k53..55 = 0;
//   k56..71 = interp ch 0..15; k72 = bias slot; k73..95 = 0
// Kernel 3: pack weights into per-lane MFMA A-fragments (f16).
// frag f: f<24 -> w1 (mf=f/3,kc=f%3); 24..55 -> w2; 56..79 -> w3
// A-frag: lane l holds W[out=16*mf+(l&15)][k=32*kc+8*(l>>4)+i], i=0..7
// ---------------------------------------------------------------------------
__global__ void pack_kernel(const float* __restrict__ w1, const float* __restrict__ b1,
                            const float* __restrict__ w2, const float* __restrict__ w3,
                            f16* __restrict__ frags) {
    int t = blockIdx.x * blockDim.x + threadIdx.x;
    if (t >= 80 * 64) return;
    int f = t >> 6, lane = t & 63;
    int g = lane >> 4, col = lane & 15;
    f16 v[8];
    if (f < 24) {
        int mf = f / 3, kc = f % 3;
        int o = mf * 16 + col;
#pragma unroll
        for (int i = 0; i < 8; i++) {
            int k = kc * 32 + g * 8 + i;
            float val = 0.f;
            if (k < 50) val = w1[(3 + k) * 128 + o];
            else if (k == 50) val = w1[0 * 128 + o];
            else if (k == 51) val = w1[1 * 128 + o];
            else if (k == 52) val = w1[2 * 128 + o];
            else if (k >= 56 && k < 72) val = w1[(53 + (k - 56)) * 128 + o];
            else if (k == 72) val = b1[o];
            v[i] = (f16)val;
        }
    } else if (f < 56) {
        int ff = f - 24, mf = ff >> 2, kc = ff & 3;
        int o = mf * 16 + col;
#pragma unroll
        for (int i = 0; i < 8; i++) {
            int k = kc * 32 + g * 8 + i;
            v[i] = (f16)w2[k * 128 + o];
        }
    } else {
        int ff = f - 56, mf = ff >> 2, kc = ff & 3;
        int o = mf * 16 + col;
#pragma unroll
        for (int i = 0; i < 8; i++) {
            int k = kc * 32 + g * 8 + i;
            v[i] = (f16)w3[k * 96 + o];
        }
    }
    f16* dst = frags + (f * 64 + lane) * 8;
#pragma unroll
    for (int i = 0; i < 8; i++) dst[i] = v[i];
}

// ---------------------------------------------------------------------------
// Kernel 4: fused interp + MLP.  1024 threads = 16 independent waves per block
// (1 block/CU, 4 waves/SIMD).  NOTE __launch_bounds__(1024, 1): the 2nd arg
// is min BLOCKS/CU (CUDA semantics) — (1024,4) forced a 64-VGPR cap and
// spilled (round 6: WRITE_SIZE 332 MB).  (1024,1) -> 128-VGPR cap, body
// needs ~120.  Weight frags in LDS (80 KB, shared); each wave does 32-pt
// batches (2 tiles of 16).  Per-wave 4-KB transition buffer doubles as the
// interp staging buffer (phases disjoint, same-wave LDS ordering).
// ---------------------------------------------------------------------------
__global__ void __launch_bounds__(1024, 1) mlp_kernel(
    const float* __restrict__ x, const float* __restrict__ s,
    const float* __restrict__ sse, const float* __restrict__ Amat,
    const float4* __restrict__ fragsv,
    const float* __restrict__ b2, const float* __restrict__ b3,
    const float* __restrict__ w4, const float* __restrict__ b4,
    float* __restrict__ out) {
    __shared__ f16 wlds[40960];        // 80 frags * 64 lanes * 8 f16 = 80 KB
    __shared__ f16 acth[16][2048];     // per-wave buffer: interp stage OR h transit
    __shared__ float bias2[128];
    __shared__ float bias3[96];
    __shared__ float w4l[96];

    const int tid = threadIdx.x;
    const int wv = tid >> 6;
    const int lane = tid & 63;
    const int g = lane >> 4, col = lane & 15;
    const int swz = (col & 7) << 3;    // f16-index swizzle bits 3..5

    {   // cooperative staging: 80KB frags + biases
        float4* wl4 = (float4*)wlds;
        for (int i = tid; i < 5120; i += 1024) wl4[i] = fragsv[i];
        if (tid < 128) bias2[tid] = b2[tid];
        if (tid < 96) { bias3[tid] = b3[tid]; w4l[tid] = w4[tid]; }
    }
    __syncthreads();
    const float b4v = b4[0];

    f16* ah = acth[wv];
    u32* ibA = (u32*)ah;               // interp staging tile A: u32 [0,192)
    u32* ibB = (u32*)ah + 192;         // tile B: u32 [192,384)  (phase-disjoint
                                       //  with TRANS use of ah)

    const int wtotal = 31250;          // 1e6 / 32
    int wg = blockIdx.x * 16 + wv;
    const int wstride = gridDim.x * 16;

    // prefetch registers (per tile): kc0 chunks, kc1 chunks, tail, coords
    f32x2v Ac0[4], Ac1[4], Ae, Axv; float Asv;
    f32x2v Bc0[4], Bc1[4], Be, Bxv; float Bsv;

    auto LOADT = [&](int pt0, f32x2v* c0, f32x2v* c1, f32x2v& e, f32x2v& xv, float& sv) {
        const float* base = sse + (long)(pt0 + col) * 50;
#pragma unroll
        for (int q = 0; q < 4; q++) c0[q] = *(const f32x2v*)(base + 8 * g + 2 * q);
        if (g < 2) {
#pragma unroll
            for (int q = 0; q < 4; q++) c1[q] = *(const f32x2v*)(base + 32 + 8 * g + 2 * q);
        } else if (g == 2) {
            e = *(const f32x2v*)(base + 48);
            sv = s[pt0 + col];
        }
        xv = *(const f32x2v*)(x + 2 * (pt0 + col));
    };

    // per-lane interp: pt=col, channels 4g..4g+3 -> ib u32 slots 2g,2g+1
    auto INTERP = [&](f32x2v xv, u32* ib) {
        float gx = fminf(fmaxf(xv.x, EPS_), 1.f - EPS_) * 127.f;
        float gy = fminf(fmaxf(xv.y, EPS_), 1.f - EPS_) * 127.f;
        float fx0 = floorf(gx), fy0 = floorf(gy);
        int ix0 = (int)fx0, iy0 = (int)fy0;
        int ix1 = min(ix0 + 1, 127), iy1 = min(iy0 + 1, 127);
        float wx = gx - fx0, wy = gy - fy0;
        const f32x4v* A4 = (const f32x4v*)Amat;
        f32x4v f00 = A4[(iy0 * 128 + ix0) * 4 + g];
        f32x4v f10 = A4[(iy0 * 128 + ix1) * 4 + g];
        f32x4v f01 = A4[(iy1 * 128 + ix0) * 4 + g];
        f32x4v f11 = A4[(iy1 * 128 + ix1) * 4 + g];
        float w00 = (1.f - wx) * (1.f - wy), w10 = wx * (1.f - wy);
        float w01 = (1.f - wx) * wy, w11 = wx * wy;
        f32x4v r = f00 * w00 + f10 * w10 + f01 * w01 + f11 * w11;
        uint2 uv;
        uv.x = bc32(pk2(r.x, r.y));
        uv.y = bc32(pk2(r.z, r.w));
        *(uint2*)(ib + col * 12 + 2 * g) = uv;
    };

    // build 3 B-frags for one tile from prefetched regs + interp buffer
    auto BUILD = [&](f32x2v* c0, f32x2v* c1, f32x2v e, f32x2v xv, float sv,
                     const u32* ib, f16x8* bf) {
        bf[0] = cvt8x2(c0[0], c0[1], c0[2], c0[3]);
        if (g < 2) {
            bf[1] = cvt8x2(c1[0], c1[1], c1[2], c1[3]);
        } else if (g == 2) {
            f16x8 t = zero8();
            t[0] = (f16)e.x; t[1] = (f16)e.y;          // sse 48,49
            t[2] = (f16)xv.x; t[3] = (f16)xv.y;        // x0,x1
            t[4] = (f16)sv;                            // s
            bf[1] = t;
        } else {
            bf[1] = *(const f16x8*)(ib + col * 12);    // interp ch 0..7
        }
        if (g == 0) {
            bf[2] = *(const f16x8*)(ib + col * 12 + 4);  // interp ch 8..15
        } else if (g == 1) {
            f16x8 t = zero8();
            t[0] = (f16)1.f;                           // k=72 bias slot
            bf[2] = t;
        } else {
            bf[2] = zero8();
        }
    };

    // C-layout (out=16mf+4g+r, pt=col) -> relu(+bias) -> ah -> B-frags of h
    auto TRANS = [&](f32x4v* acc, const float* bias, f16x8* hbf) {
#pragma unroll
        for (int mf = 0; mf < 8; mf++) {
            f32x4v v = acc[mf];
            if (bias) {
                f32x4v bb = *(const f32x4v*)&bias[mf * 16 + g * 4];
                v = v + bb;
            }
            uint2 uv;
            uv.x = bc32(pk2(fmaxf(v.x, 0.f), fmaxf(v.y, 0.f)));
            uv.y = bc32(pk2(fmaxf(v.z, 0.f), fmaxf(v.w, 0.f)));
            *(uint2*)&ah[(col * 128 + mf * 16 + g * 4) ^ swz] = uv;
        }
#pragma unroll
        for (int kc = 0; kc < 4; kc++)
            hbf[kc] = *(const f16x8*)&ah[(col * 128 + kc * 32 + g * 8) ^ swz];
    };

    auto L4OUT = [&](f32x4v* acc3, int pt0) {
        float partial = 0.f;
#pragma unroll
        for (int mf = 0; mf < 6; mf++) {
            f32x4v bb = *(const f32x4v*)&bias3[mf * 16 + g * 4];
            f32x4v wv4 = *(const f32x4v*)&w4l[mf * 16 + g * 4];
            partial += fmaxf(acc3[mf].x + bb.x, 0.f) * wv4.x;
            partial += fmaxf(acc3[mf].y + bb.y, 0.f) * wv4.y;
            partial += fmaxf(acc3[mf].z + bb.z, 0.f) * wv4.z;
            partial += fmaxf(acc3[mf].w + bb.w, 0.f) * wv4.w;
        }
        partial += __shfl_xor(partial, 16);
        partial += __shfl_xor(partial, 32);
        if (g == 0) out[pt0 + col] = partial + b4v;
    };

    if (wg < wtotal) {
        LOADT(wg * 32, Ac0, Ac1, Ae, Axv, Asv);
        LOADT(wg * 32 + 16, Bc0, Bc1, Be, Bxv, Bsv);
    }

    for (; wg < wtotal; wg += wstride) {
        const int pt0 = wg * 32;

        INTERP(Axv, ibA);
        INTERP(Bxv, ibB);

        f16x8 bfA[3], bfB[3];
        BUILD(Ac0, Ac1, Ae, Axv, Asv, ibA, bfA);
        BUILD(Bc0, Bc1, Be, Bxv, Bsv, ibB, bfB);

        // prefetch next batch (registers now free)
        int wgn = wg + wstride;
        if (wgn < wtotal) {
            LOADT(wgn * 32, Ac0, Ac1, Ae, Axv, Asv);
            LOADT(wgn * 32 + 16, Bc0, Bc1, Be, Bxv, Bsv);
        }

        // ---- Layer 1: K=96 (3 kc), 8 mf ----
        f32x4v accA[8], accB[8];
#pragma unroll
        for (int mf = 0; mf < 8; mf++) {
            accA[mf] = (f32x4v)(0.f);
            accB[mf] = (f32x4v)(0.f);
        }
#pragma unroll
        for (int kc = 0; kc < 3; kc++) {
#pragma unroll
            for (int mf = 0; mf < 8; mf++) {
                f16x8 wf = *(const f16x8*)&wlds[((mf * 3 + kc) * 64 + lane) * 8];
                accA[mf] = mfma16(wf, bfA[kc], accA[mf]);
                accB[mf] = mfma16(wf, bfB[kc], accB[mf]);
            }
        }

        f16x8 hbfA[4], hbfB[4];
        TRANS(accA, nullptr, hbfA);   // L1 bias came via k=72 slot
        TRANS(accB, nullptr, hbfB);

        // ---- Layer 2: K=128 (4 kc), 8 mf ----
        f32x4v acc2A[8], acc2B[8];
#pragma unroll
        for (int mf = 0; mf < 8; mf++) {
            acc2A[mf] = (f32x4v)(0.f);
            acc2B[mf] = (f32x4v)(0.f);
        }
#pragma unroll
        for (int kc = 0; kc < 4; kc++) {
#pragma unroll
            for (int mf = 0; mf < 8; mf++) {
                f16x8 wf = *(const f16x8*)&wlds[((24 + mf * 4 + kc) * 64 + lane) * 8];
                acc2A[mf] = mfma16(wf, hbfA[kc], acc2A[mf]);
                acc2B[mf] = mfma16(wf, hbfB[kc], acc2B[mf]);
            }
        }

        TRANS(acc2A, bias2, hbfA);
        TRANS(acc2B, bias2, hbfB);

        // ---- Layer 3: K=128 (4 kc), 6 mf ----
        f32x4v acc3A[6], acc3B[6];
#pragma unroll
        for (int mf = 0; mf < 6; mf++) {
            acc3A[mf] = (f32x4v)(0.f);
            acc3B[mf] = (f32x4v)(0.f);
        }
#pragma unroll
        for (int kc = 0; kc < 4; kc++) {
#pragma unroll
            for (int mf = 0; mf < 6; mf++) {
                f16x8 wf = *(const f16x8*)&wlds[((56 + mf * 4 + kc) * 64 + lane) * 8];
                acc3A[mf] = mfma16(wf, hbfA[kc], acc3A[mf]);
                acc3B[mf] = mfma16(wf, hbfB[kc], acc3B[mf]);
            }
        }

        // ---- Layer 4 + output ----
        L4OUT(acc3A, pt0);
        L4OUT(acc3B, pt0 + 16);
    }
}

// ---------------------------------------------------------------------------
extern "C" void kernel_launch(void* const* d_in, const int* in_sizes, int n_in,
                              void* d_out, int out_size, void* d_ws, size_t ws_size,
                              hipStream_t stream) {
    const float* x      = (const float*)d_in[0];
    const float* s      = (const float*)d_in[1];
    const float* sse    = (const float*)d_in[2];
    const float* sdf    = (const float*)d_in[3];
    const float* conv_w = (const float*)d_in[4];
    const float* conv_b = (const float*)d_in[5];
    const float* w1     = (const float*)d_in[6];
    const float* b1     = (const float*)d_in[7];
    const float* w2     = (const float*)d_in[8];
    const float* b2     = (const float*)d_in[9];
    const float* w3     = (const float*)d_in[10];
    const float* b3     = (const float*)d_in[11];
    const float* w4     = (const float*)d_in[12];
    const float* b4     = (const float*)d_in[13];
    float* out = (float*)d_out;

    float* pooled = (float*)d_ws;            // 32768 f32  [0, 131072) bytes
    float* A      = pooled + 32768;          // 262144 f32 [131072, 1179648)
    f16*   frags  = (f16*)d_ws;              // 80 KB, reuses pooled region
                                             // (written by pack AFTER conv reads pooled)

    pool_kernel<<<128, 256, 0, stream>>>(sdf, pooled);
    conv_kernel<<<64, 256, 0, stream>>>(pooled, conv_w, conv_b, A);
    pack_kernel<<<20, 256, 0, stream>>>(w1, b1, w2, w3, frags);
    mlp_kernel<<<256, 1024, 0, stream>>>(x, s, sse, A, (const float4*)frags,
                                         b2, b3, w4, b4, out);
}

// Round 8
// 135.730 us; speedup vs baseline: 1.9697x; 1.9697x over previous
//
#include <hip/hip_runtime.h>

#define EPS_ 1e-4f

typedef _Float16 f16;
typedef _Float16 f16x8 __attribute__((ext_vector_type(8)));
typedef _Float16 f16x4 __attribute__((ext_vector_type(4)));
typedef _Float16 f16x2 __attribute__((ext_vector_type(2)));
typedef __fp16 h16x2 __attribute__((ext_vector_type(2)));
typedef float f32x4v __attribute__((ext_vector_type(4)));
typedef float f32x2v __attribute__((ext_vector_type(2)));
typedef unsigned int u32;

__device__ inline f32x4v mfma16(f16x8 a, f16x8 b, f32x4v c) {
    return __builtin_amdgcn_mfma_f32_16x16x32_f16(a, b, c, 0, 0, 0);
}
__device__ inline f16x2 pk2(float a, float b) {
    h16x2 r = __builtin_amdgcn_cvt_pkrtz(a, b);
    return __builtin_bit_cast(f16x2, r);
}
__device__ inline u32 bc32(f16x2 v) { return __builtin_bit_cast(u32, v); }

__device__ inline f16x8 zero8() {
    f16x8 r;
#pragma unroll
    for (int i = 0; i < 8; i++) r[i] = (f16)0.f;
    return r;
}

__device__ inline f16x8 cvt8x2(f32x2v a, f32x2v b, f32x2v c, f32x2v d) {
    f16x2 p0 = pk2(a.x, a.y), p1 = pk2(b.x, b.y), p2 = pk2(c.x, c.y), p3 = pk2(d.x, d.y);
    f16x8 r;
    r[0] = p0[0]; r[1] = p0[1]; r[2] = p1[0]; r[3] = p1[1];
    r[4] = p2[0]; r[5] = p2[1]; r[6] = p3[0]; r[7] = p3[1];
    return r;
}

// ---------------------------------------------------------------------------
// Kernel 1: 8x8 average pool.  sdf (2,1024,1024) -> pooled (2,128,128)
// ---------------------------------------------------------------------------
__global__ void pool_kernel(const float* __restrict__ sdf, float* __restrict__ pooled) {
    int t = blockIdx.x * blockDim.x + threadIdx.x;
    int c = t >> 14;
    int rem = t & 16383;
    int R = rem >> 7;
    int C = rem & 127;
    const float* base = sdf + c * 1048576 + (R * 8) * 1024 + C * 8;
    float sum = 0.f;
#pragma unroll
    for (int r = 0; r < 8; r++) {
        const float4* p = (const float4*)(base + r * 1024);
        float4 a = p[0];
        float4 b = p[1];
        sum += a.x + a.y + a.z + a.w + b.x + b.y + b.z + b.w;
    }
    pooled[t] = sum * (1.f / 64.f);
}

// ---------------------------------------------------------------------------
// Kernel 2: 5x5 conv, 2->16 ch, pad 2. pooled (2,128,128) -> A [(y*128+x)*16+f]
// ---------------------------------------------------------------------------
__global__ void conv_kernel(const float* __restrict__ pooled,
                            const float* __restrict__ conv_w,
                            const float* __restrict__ conv_b,
                            float* __restrict__ A) {
    int t = blockIdx.x * blockDim.x + threadIdx.x;
    int y = t >> 7, x = t & 127;
    float acc[16];
#pragma unroll
    for (int f = 0; f < 16; f++) acc[f] = conv_b[f];
#pragma unroll
    for (int c = 0; c < 2; c++) {
#pragma unroll
        for (int ky = 0; ky < 5; ky++) {
            int yy = y + ky - 2;
            if (yy < 0 || yy > 127) continue;
#pragma unroll
            for (int kx = 0; kx < 5; kx++) {
                int xx = x + kx - 2;
                if (xx < 0 || xx > 127) continue;
                float v = pooled[c * 16384 + yy * 128 + xx];
                int wbase = c * 25 + ky * 5 + kx;
#pragma unroll
                for (int f = 0; f < 16; f++)
                    acc[f] = fmaf(v, conv_w[f * 50 + wbase], acc[f]);
            }
        }
    }
    float4* out4 = (float4*)(A + t * 16);
#pragma unroll
    for (int q = 0; q < 4; q++)
        out4[q] = make_float4(acc[4 * q], acc[4 * q + 1], acc[4 * q + 2], acc[4 * q + 3]);
}

// ---------------------------------------------------------------------------
// Feature (k) order for layer 1:
//   k 0..49 = sse[0..49]; k50,51 = x0,x1; k52 = s; k53..55 = 0;
//   k56..71 = interp ch 0..15; k72 = bias slot; k73..95 = 0
// Kernel 3: pack weights into per-lane MFMA A-fragments (f16).
// frag f: f<24 -> w1 (mf=f/3,kc=f%3); 24..55 -> w2; 56..79 -> w3
// A-frag: lane l holds W[out=16*mf+(l&15)][k=32*kc+8*(l>>4)+i], i=0..7
// ---------------------------------------------------------------------------
__global__ void pack_kernel(const float* __restrict__ w1, const float* __restrict__ b1,
                            const float* __restrict__ w2, const float* __restrict__ w3,
                            f16* __restrict__ frags) {
    int t = blockIdx.x * blockDim.x + threadIdx.x;
    if (t >= 80 * 64) return;
    int f = t >> 6, lane = t & 63;
    int g = lane >> 4, col = lane & 15;
    f16 v[8];
    if (f < 24) {
        int mf = f / 3, kc = f % 3;
        int o = mf * 16 + col;
#pragma unroll
        for (int i = 0; i < 8; i++) {
            int k = kc * 32 + g * 8 + i;
            float val = 0.f;
            if (k < 50) val = w1[(3 + k) * 128 + o];
            else if (k == 50) val = w1[0 * 128 + o];
            else if (k == 51) val = w1[1 * 128 + o];
            else if (k == 52) val = w1[2 * 128 + o];
            else if (k >= 56 && k < 72) val = w1[(53 + (k - 56)) * 128 + o];
            else if (k == 72) val = b1[o];
            v[i] = (f16)val;
        }
    } else if (f < 56) {
        int ff = f - 24, mf = ff >> 2, kc = ff & 3;
        int o = mf * 16 + col;
#pragma unroll
        for (int i = 0; i < 8; i++) {
            int k = kc * 32 + g * 8 + i;
            v[i] = (f16)w2[k * 128 + o];
        }
    } else {
        int ff = f - 56, mf = ff >> 2, kc = ff & 3;
        int o = mf * 16 + col;
#pragma unroll
        for (int i = 0; i < 8; i++) {
            int k = kc * 32 + g * 8 + i;
            v[i] = (f16)w3[k * 96 + o];
        }
    }
    f16* dst = frags + (f * 64 + lane) * 8;
#pragma unroll
    for (int i = 0; i < 8; i++) dst[i] = v[i];
}

// ---------------------------------------------------------------------------
// Kernel 4: fused interp + MLP.  768 threads = 12 waves/block, 1 block/CU,
// 3 waves/SIMD.  Flat-workgroup-size register caps (measured r6/r7): 1024thr
// -> 128 unified regs/wave (spills), 768thr -> 168, 512thr -> 256.  This body
// needs ~90 arch VGPR + 64 AGPR after dropping the cross-iter sse prefetch
// (kept only the 4-reg xv coordinate prefetch); TLP from 3 waves/SIMD covers
// the load latency instead.  Weight frags in LDS (80 KB shared); 32 pts/wave
// per iteration (2 tiles).  Per-wave 4-KB transition buffer doubles as the
// interp staging buffer (phases disjoint, same-wave LDS ordering).
// ---------------------------------------------------------------------------
__global__ void __launch_bounds__(768, 3) mlp_kernel(
    const float* __restrict__ x, const float* __restrict__ s,
    const float* __restrict__ sse, const float* __restrict__ Amat,
    const float4* __restrict__ fragsv,
    const float* __restrict__ b2, const float* __restrict__ b3,
    const float* __restrict__ w4, const float* __restrict__ b4,
    float* __restrict__ out) {
    __shared__ f16 wlds[40960];        // 80 frags * 64 lanes * 8 f16 = 80 KB
    __shared__ f16 acth[12][2048];     // per-wave buffer: interp stage OR h transit
    __shared__ float bias2[128];
    __shared__ float bias3[96];
    __shared__ float w4l[96];

    const int tid = threadIdx.x;
    const int wv = tid >> 6;
    const int lane = tid & 63;
    const int g = lane >> 4, col = lane & 15;
    const int swz = (col & 7) << 3;    // f16-index swizzle bits 3..5

    {   // cooperative staging: 80KB frags + biases
        float4* wl4 = (float4*)wlds;
        for (int i = tid; i < 5120; i += 768) wl4[i] = fragsv[i];
        if (tid < 128) bias2[tid] = b2[tid];
        if (tid < 96) { bias3[tid] = b3[tid]; w4l[tid] = w4[tid]; }
    }
    __syncthreads();
    const float b4v = b4[0];

    f16* ah = acth[wv];
    u32* ibA = (u32*)ah;               // interp staging tile A: u32 [0,192)
    u32* ibB = (u32*)ah + 192;         // tile B: u32 [192,384)

    const int wtotal = 31250;          // 1e6 / 32
    int wg = blockIdx.x * 12 + wv;
    const int wstride = gridDim.x * 12;

    f32x2v Axv, Bxv;                   // only the coords are prefetched

    // per-lane interp: pt=col, channels 4g..4g+3 -> ib u32 slots 2g,2g+1
    auto INTERP = [&](f32x2v xv, u32* ib) {
        float gx = fminf(fmaxf(xv.x, EPS_), 1.f - EPS_) * 127.f;
        float gy = fminf(fmaxf(xv.y, EPS_), 1.f - EPS_) * 127.f;
        float fx0 = floorf(gx), fy0 = floorf(gy);
        int ix0 = (int)fx0, iy0 = (int)fy0;
        int ix1 = min(ix0 + 1, 127), iy1 = min(iy0 + 1, 127);
        float wx = gx - fx0, wy = gy - fy0;
        const f32x4v* A4 = (const f32x4v*)Amat;
        f32x4v f00 = A4[(iy0 * 128 + ix0) * 4 + g];
        f32x4v f10 = A4[(iy0 * 128 + ix1) * 4 + g];
        f32x4v f01 = A4[(iy1 * 128 + ix0) * 4 + g];
        f32x4v f11 = A4[(iy1 * 128 + ix1) * 4 + g];
        float w00 = (1.f - wx) * (1.f - wy), w10 = wx * (1.f - wy);
        float w01 = (1.f - wx) * wy, w11 = wx * wy;
        f32x4v r = f00 * w00 + f10 * w10 + f01 * w01 + f11 * w11;
        uint2 uv;
        uv.x = bc32(pk2(r.x, r.y));
        uv.y = bc32(pk2(r.z, r.w));
        *(uint2*)(ib + col * 12 + 2 * g) = uv;
    };

    // load sse/s for one tile and build its 3 B-frags (raw temps die here)
    auto LOADBUILD = [&](int pt0, f32x2v xv, const u32* ib, f16x8* bf) {
        const float* base = sse + (long)(pt0 + col) * 50;
        f32x2v c0[4];
#pragma unroll
        for (int q = 0; q < 4; q++) c0[q] = *(const f32x2v*)(base + 8 * g + 2 * q);
        bf[0] = cvt8x2(c0[0], c0[1], c0[2], c0[3]);
        if (g < 2) {
            f32x2v c1[4];
#pragma unroll
            for (int q = 0; q < 4; q++) c1[q] = *(const f32x2v*)(base + 32 + 8 * g + 2 * q);
            bf[1] = cvt8x2(c1[0], c1[1], c1[2], c1[3]);
        } else if (g == 2) {
            f32x2v e = *(const f32x2v*)(base + 48);
            float sv = s[pt0 + col];
            f16x8 t = zero8();
            t[0] = (f16)e.x; t[1] = (f16)e.y;          // sse 48,49
            t[2] = (f16)xv.x; t[3] = (f16)xv.y;        // x0,x1
            t[4] = (f16)sv;                            // s
            bf[1] = t;
        } else {
            bf[1] = *(const f16x8*)(ib + col * 12);    // interp ch 0..7
        }
        if (g == 0) {
            bf[2] = *(const f16x8*)(ib + col * 12 + 4);  // interp ch 8..15
        } else if (g == 1) {
            f16x8 t = zero8();
            t[0] = (f16)1.f;                           // k=72 bias slot
            bf[2] = t;
        } else {
            bf[2] = zero8();
        }
    };

    // C-layout (out=16mf+4g+r, pt=col) -> relu(+bias) -> ah -> B-frags of h
    auto TRANS = [&](f32x4v* acc, const float* bias, f16x8* hbf) {
#pragma unroll
        for (int mf = 0; mf < 8; mf++) {
            f32x4v v = acc[mf];
            if (bias) {
                f32x4v bb = *(const f32x4v*)&bias[mf * 16 + g * 4];
                v = v + bb;
            }
            uint2 uv;
            uv.x = bc32(pk2(fmaxf(v.x, 0.f), fmaxf(v.y, 0.f)));
            uv.y = bc32(pk2(fmaxf(v.z, 0.f), fmaxf(v.w, 0.f)));
            *(uint2*)&ah[(col * 128 + mf * 16 + g * 4) ^ swz] = uv;
        }
#pragma unroll
        for (int kc = 0; kc < 4; kc++)
            hbf[kc] = *(const f16x8*)&ah[(col * 128 + kc * 32 + g * 8) ^ swz];
    };

    auto L4OUT = [&](f32x4v* acc3, int pt0) {
        float partial = 0.f;
#pragma unroll
        for (int mf = 0; mf < 6; mf++) {
            f32x4v bb = *(const f32x4v*)&bias3[mf * 16 + g * 4];
            f32x4v wv4 = *(const f32x4v*)&w4l[mf * 16 + g * 4];
            partial += fmaxf(acc3[mf].x + bb.x, 0.f) * wv4.x;
            partial += fmaxf(acc3[mf].y + bb.y, 0.f) * wv4.y;
            partial += fmaxf(acc3[mf].z + bb.z, 0.f) * wv4.z;
            partial += fmaxf(acc3[mf].w + bb.w, 0.f) * wv4.w;
        }
        partial += __shfl_xor(partial, 16);
        partial += __shfl_xor(partial, 32);
        if (g == 0) out[pt0 + col] = partial + b4v;
    };

    if (wg < wtotal) {
        Axv = *(const f32x2v*)(x + 2 * (wg * 32 + col));
        Bxv = *(const f32x2v*)(x + 2 * (wg * 32 + 16 + col));
    }

    for (; wg < wtotal; wg += wstride) {
        const int pt0 = wg * 32;

        // ---- interp gathers first (temps don't overlap sse raw temps) ----
        INTERP(Axv, ibA);
        INTERP(Bxv, ibB);

        // ---- load + build B-frags (raw temps die inside) ----
        f16x8 bfA[3], bfB[3];
        LOADBUILD(pt0, Axv, ibA, bfA);
        LOADBUILD(pt0 + 16, Bxv, ibB, bfB);

        // ---- prefetch next coords only (4 regs) ----
        int wgn = wg + wstride;
        if (wgn < wtotal) {
            Axv = *(const f32x2v*)(x + 2 * (wgn * 32 + col));
            Bxv = *(const f32x2v*)(x + 2 * (wgn * 32 + 16 + col));
        }

        // ---- Layer 1: K=96 (3 kc), 8 mf ----
        f32x4v accA[8], accB[8];
#pragma unroll
        for (int mf = 0; mf < 8; mf++) {
            accA[mf] = (f32x4v)(0.f);
            accB[mf] = (f32x4v)(0.f);
        }
#pragma unroll
        for (int kc = 0; kc < 3; kc++) {
#pragma unroll
            for (int mf = 0; mf < 8; mf++) {
                f16x8 wf = *(const f16x8*)&wlds[((mf * 3 + kc) * 64 + lane) * 8];
                accA[mf] = mfma16(wf, bfA[kc], accA[mf]);
                accB[mf] = mfma16(wf, bfB[kc], accB[mf]);
            }
        }

        f16x8 hbfA[4], hbfB[4];
        TRANS(accA, nullptr, hbfA);   // L1 bias came via k=72 slot
        TRANS(accB, nullptr, hbfB);

        // ---- Layer 2: K=128 (4 kc), 8 mf ----
        f32x4v acc2A[8], acc2B[8];
#pragma unroll
        for (int mf = 0; mf < 8; mf++) {
            acc2A[mf] = (f32x4v)(0.f);
            acc2B[mf] = (f32x4v)(0.f);
        }
#pragma unroll
        for (int kc = 0; kc < 4; kc++) {
#pragma unroll
            for (int mf = 0; mf < 8; mf++) {
                f16x8 wf = *(const f16x8*)&wlds[((24 + mf * 4 + kc) * 64 + lane) * 8];
                acc2A[mf] = mfma16(wf, hbfA[kc], acc2A[mf]);
                acc2B[mf] = mfma16(wf, hbfB[kc], acc2B[mf]);
            }
        }

        TRANS(acc2A, bias2, hbfA);
        TRANS(acc2B, bias2, hbfB);

        // ---- Layer 3: K=128 (4 kc), 6 mf ----
        f32x4v acc3A[6], acc3B[6];
#pragma unroll
        for (int mf = 0; mf < 6; mf++) {
            acc3A[mf] = (f32x4v)(0.f);
            acc3B[mf] = (f32x4v)(0.f);
        }
#pragma unroll
        for (int kc = 0; kc < 4; kc++) {
#pragma unroll
            for (int mf = 0; mf < 6; mf++) {
                f16x8 wf = *(const f16x8*)&wlds[((56 + mf * 4 + kc) * 64 + lane) * 8];
                acc3A[mf] = mfma16(wf, hbfA[kc], acc3A[mf]);
                acc3B[mf] = mfma16(wf, hbfB[kc], acc3B[mf]);
            }
        }

        // ---- Layer 4 + output ----
        L4OUT(acc3A, pt0);
        L4OUT(acc3B, pt0 + 16);
    }
}

// ---------------------------------------------------------------------------
extern "C" void kernel_launch(void* const* d_in, const int* in_sizes, int n_in,
                              void* d_out, int out_size, void* d_ws, size_t ws_size,
                              hipStream_t stream) {
    const float* x      = (const float*)d_in[0];
    const float* s      = (const float*)d_in[1];
    const float* sse    = (const float*)d_in[2];
    const float* sdf    = (const float*)d_in[3];
    const float* conv_w = (const float*)d_in[4];
    const float* conv_b = (const float*)d_in[5];
    const float* w1     = (const float*)d_in[6];
    const float* b1     = (const float*)d_in[7];
    const float* w2     = (const float*)d_in[8];
    const float* b2     = (const float*)d_in[9];
    const float* w3     = (const float*)d_in[10];
    const float* b3     = (const float*)d_in[11];
    const float* w4     = (const float*)d_in[12];
    const float* b4     = (const float*)d_in[13];
    float* out = (float*)d_out;

    float* pooled = (float*)d_ws;            // 32768 f32  [0, 131072) bytes
    float* A      = pooled + 32768;          // 262144 f32 [131072, 1179648)
    f16*   frags  = (f16*)d_ws;              // 80 KB, reuses pooled region
                                             // (written by pack AFTER conv reads pooled)

    pool_kernel<<<128, 256, 0, stream>>>(sdf, pooled);
    conv_kernel<<<64, 256, 0, stream>>>(pooled, conv_w, conv_b, A);
    pack_kernel<<<20, 256, 0, stream>>>(w1, b1, w2, w3, frags);
    mlp_kernel<<<256, 768, 0, stream>>>(x, s, sse, A, (const float4*)frags,
                                        b2, b3, w4, b4, out);
}